// Round 5
// baseline (702.297 us; speedup 1.0000x reference)
//
#include <hip/hip_runtime.h>

constexpr int T = 4096;
constexpr int C = 1024;
constexpr int D = 256;
constexpr int VOCAB = 32000;
constexpr int VT = 64;                 // vocab cols per tile
constexpr int NVT = VOCAB / VT;        // 500 vocab tiles
constexpr int SENT = 0x7FFFFFFF;

typedef __attribute__((ext_vector_type(8))) short bf16x8;
typedef __attribute__((ext_vector_type(4))) float f32x4;

__device__ inline unsigned short f2bf(float f) {
    union { float f; unsigned int u; } v; v.f = f;
    unsigned int u = v.u + 0x7FFFu + ((v.u >> 16) & 1u);   // RTNE
    return (unsigned short)(u >> 16);
}
// async global->LDS, 16B/lane; LDS dest = wave-uniform base + lane*16
__device__ inline void gl_lds16(const unsigned short* g, unsigned short* l) {
    __builtin_amdgcn_global_load_lds(
        (const __attribute__((address_space(1))) unsigned int*)g,
        (__attribute__((address_space(3))) unsigned int*)l, 16, 0, 0);
}

// ---------------------------------------------------------------------------
// Prep: blocks [0,2048): x fp32 -> bf16; blocks [2048,2176): W -> WT transposed
// ---------------------------------------------------------------------------
__global__ __launch_bounds__(256) void prep_kernel(
    const float* __restrict__ x,
    const float* __restrict__ Wq, const float* __restrict__ Wk,
    unsigned short* __restrict__ xb, unsigned short* __restrict__ WT)
{
    const int tid = threadIdx.x;
    if (blockIdx.x < 2048) {
        const int i = (blockIdx.x * 256 + tid) * 8;
        float4 a = *(const float4*)(x + i);
        float4 b = *(const float4*)(x + i + 4);
        union { bf16x8 v; unsigned short s[8]; } o;
        o.s[0] = f2bf(a.x); o.s[1] = f2bf(a.y); o.s[2] = f2bf(a.z); o.s[3] = f2bf(a.w);
        o.s[4] = f2bf(b.x); o.s[5] = f2bf(b.y); o.s[6] = f2bf(b.z); o.s[7] = f2bf(b.w);
        *(bf16x8*)(xb + i) = o.v;
    } else {
        const int bid = blockIdx.x - 2048;
        const int w  = bid >> 6;
        const int rem = bid & 63;
        const int k0 = (rem >> 2) * 64;
        const int n0 = (rem & 3) * 64;
        const float* W = w ? Wk : Wq;
        __shared__ float tile[64][65];
        #pragma unroll
        for (int p = 0; p < 16; ++p) {
            const int e = p * 256 + tid;
            const int r = e >> 6, c = e & 63;
            tile[c][r] = W[(size_t)(k0 + r) * D + n0 + c];
        }
        __syncthreads();
        #pragma unroll
        for (int p = 0; p < 2; ++p) {
            const int e = p * 256 + tid;
            const int rr = e >> 3, cc = e & 7;
            union { bf16x8 v; unsigned short s[8]; } o;
            #pragma unroll
            for (int i = 0; i < 8; ++i) o.s[i] = f2bf(tile[rr][cc * 8 + i]);
            *(bf16x8*)(WT + (size_t)(w * D + n0 + rr) * C + k0 + cc * 8) = o.v;
        }
    }
}

// ---------------------------------------------------------------------------
// Bucket build: group j's by vocab tile of idx[j]. Entry = (j<<6)|(idx&63).
// One block, 256 threads.
// ---------------------------------------------------------------------------
__global__ __launch_bounds__(256) void bucket_kernel(
    const int* __restrict__ idx, int* __restrict__ offs, int* __restrict__ lists)
{
    __shared__ int cnt[NVT];
    __shared__ int base_s[NVT];
    const int tid = threadIdx.x;
    for (int v = tid; v < NVT; v += 256) cnt[v] = 0;
    __syncthreads();
    for (int j = tid; j < T; j += 256) atomicAdd(&cnt[idx[j] / VT], 1);
    __syncthreads();
    if (tid == 0) {
        int run = 0;
        for (int v = 0; v < NVT; ++v) { base_s[v] = run; run += cnt[v]; }
    }
    __syncthreads();
    for (int v = tid; v < NVT; v += 256) offs[v] = base_s[v];
    if (tid == 0) offs[NVT] = T;
    __syncthreads();
    for (int v = tid; v < NVT; v += 256) cnt[v] = 0;   // reuse as cursor
    __syncthreads();
    for (int j = tid; j < T; j += 256) {
        const int v = idx[j] / VT;
        const int pos = atomicAdd(&cnt[v], 1);
        lists[base_s[v] + pos] = (j << 6) | (idx[j] & (VT - 1));
    }
}

// ---------------------------------------------------------------------------
// Kernel 1: qk[T][512] bf16 = xb[T][C] @ WT[512][C]^T  (16x16x32 bf16 MFMA)
// ---------------------------------------------------------------------------
__global__ __launch_bounds__(256) void qk_mfma_kernel(
    const unsigned short* __restrict__ xb,
    const unsigned short* __restrict__ WT,
    unsigned short* __restrict__ qk)
{
    const int m0 = blockIdx.x * 64, n0 = blockIdx.y * 64;
    __shared__ __align__(16) unsigned short As[64 * 64];
    __shared__ __align__(16) unsigned short Bs[64 * 64];
    const int tid = threadIdx.x;
    const int wave = tid >> 6, lane = tid & 63;
    const int quad = lane >> 4, lr = lane & 15;
    const int wm = wave >> 1, wn = wave & 1;
    const int rsub = lane >> 3, c8 = (lane & 7) * 8;

    f32x4 acc[2][2] = {};

    for (int k0 = 0; k0 < C; k0 += 64) {
        #pragma unroll
        for (int q = 0; q < 2; ++q) {
            const int ch = wave * 2 + q;
            const int r = ch * 8 + rsub;
            gl_lds16(xb + (size_t)(m0 + r) * C + k0 + c8, As + ch * 512);
            gl_lds16(WT + (size_t)(n0 + r) * C + k0 + c8, Bs + ch * 512);
        }
        __syncthreads();
        #pragma unroll
        for (int kk = 0; kk < 64; kk += 32) {
            bf16x8 a[2], b[2];
            #pragma unroll
            for (int s = 0; s < 2; ++s) {
                a[s] = *(const bf16x8*)(As + (wm * 32 + s * 16 + lr) * 64 + kk + quad * 8);
                b[s] = *(const bf16x8*)(Bs + (wn * 32 + s * 16 + lr) * 64 + kk + quad * 8);
            }
            #pragma unroll
            for (int i = 0; i < 2; ++i)
                #pragma unroll
                for (int j = 0; j < 2; ++j)
                    acc[i][j] = __builtin_amdgcn_mfma_f32_16x16x32_bf16(
                        a[i], b[j], acc[i][j], 0, 0, 0);
        }
        __syncthreads();
    }

    #pragma unroll
    for (int i = 0; i < 2; ++i)
        #pragma unroll
        for (int j = 0; j < 2; ++j)
            #pragma unroll
            for (int r = 0; r < 4; ++r) {
                const int row = m0 + wm * 32 + i * 16 + quad * 4 + r;
                const int col = n0 + wn * 32 + j * 16 + lr;
                qk[(size_t)row * 512 + col] = f2bf(acc[i][j][r]);
            }
}

// ---------------------------------------------------------------------------
// Fused QK^T + scatter: block (ti, vt). Stage q-tile (64x256) in LDS, gather
// bucket's k-rows, MFMA the needed c columns, causal-mask + scatter into a
// 64x64 fp32 LDS out-tile, stream tile to out. c never touches memory.
// ---------------------------------------------------------------------------
__global__ __launch_bounds__(256) void scatter_mfma_kernel(
    const unsigned short* __restrict__ qk,
    const int* __restrict__ offs,
    const int* __restrict__ lists,
    float* __restrict__ out)
{
    __shared__ __align__(16) unsigned short As[64 * 256];   // 32 KB q-tile
    __shared__ __align__(16) unsigned short Bs[16 * 256];   // 8 KB k-rows
    __shared__ __align__(16) float Ot[64 * VT];             // 16 KB out-tile
    __shared__ int jent[16];

    const int ti = blockIdx.x;
    const int vt = blockIdx.y;
    const int tid = threadIdx.x;
    const int wave = tid >> 6, lane = tid & 63;
    const int quad = lane >> 4, lr = lane & 15;

    // stage A = q rows [ti*64, +64), cols 0..255 (async DMA)
    const unsigned short* qbase = qk + (size_t)ti * 64 * 512;
    #pragma unroll
    for (int p = 0; p < 8; ++p) {
        const int r = p * 8 + wave * 2 + (lane >> 5);
        gl_lds16(qbase + (size_t)r * 512 + (lane & 31) * 8,
                 As + (p * 8 + wave * 2) * 256);
    }
    // zero out-tile while DMA is in flight
    f32x4* Ot4 = (f32x4*)Ot;
    const f32x4 z4 = {0.0f, 0.0f, 0.0f, 0.0f};
    #pragma unroll
    for (int i = 0; i < 4; ++i) Ot4[i * 256 + tid] = z4;

    const int off0 = offs[vt], off1 = offs[vt + 1];
    const float scale = 1.0f / 256.0f;

    for (int g = off0; g < off1; g += 16) {
        if (tid < 16) jent[tid] = (g + tid < off1) ? lists[g + tid] : SENT;
        __syncthreads();                       // jent ready; A/B DMA drained; prev scatter done
        // gather 16 k-rows into Bs
        #pragma unroll
        for (int p = 0; p < 2; ++p) {
            const int rl = p * 8 + wave * 2 + (lane >> 5);
            int j = jent[rl] >> 6; if (j > T - 1) j = 0;
            gl_lds16(qk + (size_t)j * 512 + 256 + (lane & 31) * 8,
                     Bs + (p * 8 + wave * 2) * 256);
        }
        __syncthreads();                       // B ready (barrier drains vmcnt)

        // wave handles rows [wave*16, +16); K=256 in 8 steps
        f32x4 acc = {0.0f, 0.0f, 0.0f, 0.0f};
        #pragma unroll
        for (int k0 = 0; k0 < 256; k0 += 32) {
            bf16x8 a = *(const bf16x8*)(As + (wave * 16 + lr) * 256 + k0 + quad * 8);
            bf16x8 b = *(const bf16x8*)(Bs + lr * 256 + k0 + quad * 8);
            acc = __builtin_amdgcn_mfma_f32_16x16x32_bf16(a, b, acc, 0, 0, 0);
        }
        // scatter: C/D layout col=lane&15 (j slot), row=quad*4+reg
        const int e = jent[lr];
        const int j = e >> 6, lc = e & (VT - 1);
        #pragma unroll
        for (int r = 0; r < 4; ++r) {
            const int rloc = wave * 16 + quad * 4 + r;
            const int t = ti * 64 + rloc;
            if (j <= t) atomicAdd(&Ot[rloc * VT + lc], acc[r] * scale);
        }
        __syncthreads();                       // scatter done before jent/Bs reuse
    }
    __syncthreads();

    // stream the 64x64 tile out
    float* obase = out + (size_t)ti * 64 * VOCAB + (size_t)vt * VT;
    #pragma unroll
    for (int i = 0; i < 4; ++i) {
        const int q4 = i * 256 + tid;          // 0..1023 f32x4 chunks
        const int rloc = q4 >> 4, c4 = q4 & 15;
        __builtin_nontemporal_store(Ot4[q4],
            (f32x4*)(obase + (size_t)rloc * VOCAB + c4 * 4));
    }
}

// ---------------------------------------------------------------------------
extern "C" void kernel_launch(void* const* d_in, const int* in_sizes, int n_in,
                              void* d_out, int out_size, void* d_ws, size_t ws_size,
                              hipStream_t stream)
{
    const float* x   = (const float*)d_in[0];
    const int*   idx = (const int*)d_in[1];
    const float* Wq  = (const float*)d_in[2];
    const float* Wk  = (const float*)d_in[3];
    float* out = (float*)d_out;

    // ws: xb 8MB | WT 1MB | qk 4MB | lists 16KB | offs 2KB
    unsigned short* xb = (unsigned short*)d_ws;
    unsigned short* WT = xb + (size_t)T * C;
    unsigned short* qk = WT + (size_t)2 * D * C;
    int* lists = (int*)(qk + (size_t)T * 2 * D);
    int* offs  = lists + T;

    prep_kernel<<<dim3(2048 + 128), 256, 0, stream>>>(x, Wq, Wk, xb, WT);
    bucket_kernel<<<dim3(1), 256, 0, stream>>>(idx, offs, lists);
    qk_mfma_kernel<<<dim3(T / 64, (2 * D) / 64), 256, 0, stream>>>(xb, WT, qk);
    scatter_mfma_kernel<<<dim3(T / 64, NVT), 256, 0, stream>>>(qk, offs, lists, out);
}

// Round 6
// 561.618 us; speedup vs baseline: 1.2505x; 1.2505x over previous
//
#include <hip/hip_runtime.h>
#include <math.h>

constexpr int T = 4096;
constexpr int C = 1024;
constexpr int D = 256;
constexpr int VOCAB = 32000;
constexpr int VQ = VOCAB / 4;              // 8000 floats = 31.25 KB LDS
constexpr int NT = T / 64;
constexpr int NTILES = NT * (NT + 1) / 2;  // 2080 causal tiles

typedef __attribute__((ext_vector_type(8))) short bf16x8;
typedef __attribute__((ext_vector_type(4))) float f32x4;

__device__ inline unsigned short f2bf(float f) {
    union { float f; unsigned int u; } v; v.f = f;
    unsigned int u = v.u + 0x7FFFu + ((v.u >> 16) & 1u);   // RTNE
    return (unsigned short)(u >> 16);
}
__device__ inline float bf2f(unsigned short s) {
    union { unsigned int u; float f; } v; v.u = ((unsigned int)s) << 16;
    return v.f;
}
// async global->LDS, 16B per lane; LDS dest = wave-uniform base + lane*16
__device__ inline void gl_lds16(const unsigned short* g, unsigned short* l) {
    __builtin_amdgcn_global_load_lds(
        (const __attribute__((address_space(1))) unsigned int*)g,
        (__attribute__((address_space(3))) unsigned int*)l, 16, 0, 0);
}

// ---------------------------------------------------------------------------
// Prep: blocks [0,2048): x fp32 -> bf16 (8 elems/thread)
//       blocks [2048,2176): W [C][D] fp32 -> WT [512][C] bf16 transposed
// ---------------------------------------------------------------------------
__global__ __launch_bounds__(256) void prep_kernel(
    const float* __restrict__ x,
    const float* __restrict__ Wq, const float* __restrict__ Wk,
    unsigned short* __restrict__ xb, unsigned short* __restrict__ WT)
{
    const int tid = threadIdx.x;
    if (blockIdx.x < 2048) {
        const int i = (blockIdx.x * 256 + tid) * 8;
        float4 a = *(const float4*)(x + i);
        float4 b = *(const float4*)(x + i + 4);
        union { bf16x8 v; unsigned short s[8]; } o;
        o.s[0] = f2bf(a.x); o.s[1] = f2bf(a.y); o.s[2] = f2bf(a.z); o.s[3] = f2bf(a.w);
        o.s[4] = f2bf(b.x); o.s[5] = f2bf(b.y); o.s[6] = f2bf(b.z); o.s[7] = f2bf(b.w);
        *(bf16x8*)(xb + i) = o.v;
    } else {
        const int bid = blockIdx.x - 2048;        // 128 blocks
        const int w  = bid >> 6;                  // 0=Wq, 1=Wk
        const int rem = bid & 63;
        const int k0 = (rem >> 2) * 64;           // 16 k-tiles
        const int n0 = (rem & 3) * 64;            // 4 n-tiles
        const float* W = w ? Wk : Wq;
        __shared__ float tile[64][65];
        #pragma unroll
        for (int p = 0; p < 16; ++p) {
            const int e = p * 256 + tid;
            const int r = e >> 6, c = e & 63;
            tile[c][r] = W[(size_t)(k0 + r) * D + n0 + c];
        }
        __syncthreads();
        #pragma unroll
        for (int p = 0; p < 2; ++p) {
            const int e = p * 256 + tid;
            const int rr = e >> 3, cc = e & 7;
            union { bf16x8 v; unsigned short s[8]; } o;
            #pragma unroll
            for (int i = 0; i < 8; ++i) o.s[i] = f2bf(tile[rr][cc * 8 + i]);
            *(bf16x8*)(WT + (size_t)(w * D + n0 + rr) * C + k0 + cc * 8) = o.v;
        }
    }
}

// ---------------------------------------------------------------------------
// Kernel 1: qk[T][512] bf16 = xb[T][C] @ WT[512][C]^T
// 64x64 tile, 4 waves 2x2, BK=64, raw K-major LDS + global_load_lds(16B).
// ---------------------------------------------------------------------------
__global__ __launch_bounds__(256) void qk_mfma_kernel(
    const unsigned short* __restrict__ xb,
    const unsigned short* __restrict__ WT,
    unsigned short* __restrict__ qk)
{
    const int m0 = blockIdx.x * 64, n0 = blockIdx.y * 64;
    __shared__ __align__(16) unsigned short As[64 * 64];
    __shared__ __align__(16) unsigned short Bs[64 * 64];
    const int tid = threadIdx.x;
    const int wave = tid >> 6, lane = tid & 63;
    const int quad = lane >> 4, lr = lane & 15;
    const int wm = wave >> 1, wn = wave & 1;
    const int rsub = lane >> 3, c8 = (lane & 7) * 8;   // staging lane map

    f32x4 acc[2][2] = {};

    for (int k0 = 0; k0 < C; k0 += 64) {
        #pragma unroll
        for (int q = 0; q < 2; ++q) {
            const int ch = wave * 2 + q;               // 0..7, 8 rows each
            const int r = ch * 8 + rsub;
            gl_lds16(xb + (size_t)(m0 + r) * C + k0 + c8, As + ch * 512);
            gl_lds16(WT + (size_t)(n0 + r) * C + k0 + c8, Bs + ch * 512);
        }
        __syncthreads();
        #pragma unroll
        for (int kk = 0; kk < 64; kk += 32) {
            bf16x8 a[2], b[2];
            #pragma unroll
            for (int s = 0; s < 2; ++s) {
                a[s] = *(const bf16x8*)(As + (wm * 32 + s * 16 + lr) * 64 + kk + quad * 8);
                b[s] = *(const bf16x8*)(Bs + (wn * 32 + s * 16 + lr) * 64 + kk + quad * 8);
            }
            #pragma unroll
            for (int i = 0; i < 2; ++i)
                #pragma unroll
                for (int j = 0; j < 2; ++j)
                    acc[i][j] = __builtin_amdgcn_mfma_f32_16x16x32_bf16(
                        a[i], b[j], acc[i][j], 0, 0, 0);
        }
        __syncthreads();
    }

    #pragma unroll
    for (int i = 0; i < 2; ++i)
        #pragma unroll
        for (int j = 0; j < 2; ++j)
            #pragma unroll
            for (int r = 0; r < 4; ++r) {
                const int row = m0 + wm * 32 + i * 16 + quad * 4 + r;
                const int col = n0 + wn * 32 + j * 16 + lr;
                qk[(size_t)row * 512 + col] = f2bf(acc[i][j][r]);
            }
}

// ---------------------------------------------------------------------------
// Kernel 2: causal 64x64 tiles of c = (q @ k^T)/256, masked, written as
// bf16 packed row-contiguous: row t=(ti*64+il) at tbase(ti)+il*len, len=(ti+1)*64.
// ---------------------------------------------------------------------------
__global__ __launch_bounds__(256) void qkt_mfma_kernel(
    const unsigned short* __restrict__ qk,
    unsigned short* __restrict__ cpack)
{
    const int bid = blockIdx.x;
    int ti = (int)((sqrtf(8.0f * (float)bid + 1.0f) - 1.0f) * 0.5f);
    while ((ti + 1) * (ti + 2) / 2 <= bid) ++ti;
    while (ti * (ti + 1) / 2 > bid) --ti;
    const int tj = bid - ti * (ti + 1) / 2;

    __shared__ __align__(16) unsigned short As[64 * 64];
    __shared__ __align__(16) unsigned short Bs[64 * 64];
    const int tid = threadIdx.x;
    const int wave = tid >> 6, lane = tid & 63;
    const int quad = lane >> 4, lr = lane & 15;
    const int wm = wave >> 1, wn = wave & 1;
    const int rsub = lane >> 3, c8 = (lane & 7) * 8;

    f32x4 acc[2][2] = {};

    const unsigned short* qp = qk + (size_t)ti * 64 * 512;        // q part
    const unsigned short* kp = qk + (size_t)tj * 64 * 512 + 256;  // k part

    for (int k0 = 0; k0 < D; k0 += 64) {
        #pragma unroll
        for (int q = 0; q < 2; ++q) {
            const int ch = wave * 2 + q;
            const int r = ch * 8 + rsub;
            gl_lds16(qp + (size_t)r * 512 + k0 + c8, As + ch * 512);
            gl_lds16(kp + (size_t)r * 512 + k0 + c8, Bs + ch * 512);
        }
        __syncthreads();
        #pragma unroll
        for (int kk = 0; kk < 64; kk += 32) {
            bf16x8 a[2], b[2];
            #pragma unroll
            for (int s = 0; s < 2; ++s) {
                a[s] = *(const bf16x8*)(As + (wm * 32 + s * 16 + lr) * 64 + kk + quad * 8);
                b[s] = *(const bf16x8*)(Bs + (wn * 32 + s * 16 + lr) * 64 + kk + quad * 8);
            }
            #pragma unroll
            for (int i = 0; i < 2; ++i)
                #pragma unroll
                for (int j = 0; j < 2; ++j)
                    acc[i][j] = __builtin_amdgcn_mfma_f32_16x16x32_bf16(
                        a[i], b[j], acc[i][j], 0, 0, 0);
        }
        __syncthreads();
    }

    // epilogue: mask+scale -> bf16 tile in LDS (reuse As), then packed write
    const float scale = 1.0f / 256.0f;
    unsigned short* Cs = As;
    #pragma unroll
    for (int i = 0; i < 2; ++i)
        #pragma unroll
        for (int j = 0; j < 2; ++j)
            #pragma unroll
            for (int r = 0; r < 4; ++r) {
                const int row = wm * 32 + i * 16 + quad * 4 + r;
                const int col = wn * 32 + j * 16 + lr;
                const int rg = ti * 64 + row, cg = tj * 64 + col;
                Cs[row * 64 + col] = f2bf((cg <= rg) ? acc[i][j][r] * scale : 0.0f);
            }
    __syncthreads();

    const size_t tbase = (size_t)4096 * ((size_t)ti * (ti + 1) / 2);
    const int len = (ti + 1) * 64;
    #pragma unroll
    for (int p = 0; p < 2; ++p) {
        const int cidx = p * 256 + tid;        // 512 chunks of 16B
        const int row = cidx >> 3, o8 = (cidx & 7) * 8;
        *(bf16x8*)(cpack + tbase + (size_t)row * len + tj * 64 + o8) =
            *(const bf16x8*)(Cs + row * 64 + o8);
    }
}

// ---------------------------------------------------------------------------
// Kernel 3: one block per (row t, vocab quarter). LDS histogram + dense
// nontemporal write. 31.25 KB LDS, 512 thr -> 4 blocks/CU = 32 waves/CU.
// ---------------------------------------------------------------------------
__global__ __launch_bounds__(512) void row_scatter_kernel(
    const unsigned short* __restrict__ cpack,
    const int* __restrict__ idx,
    float* __restrict__ out)
{
    __shared__ f32x4 hist4[VQ / 4];            // 31.25 KB
    float* hist = (float*)hist4;

    const int t  = blockIdx.x;
    const int lo = blockIdx.y * VQ;
    const int tid = threadIdx.x;

    const f32x4 z4 = {0.0f, 0.0f, 0.0f, 0.0f};
    for (int v = tid; v < VQ / 4; v += 512) hist4[v] = z4;
    __syncthreads();

    const int ti = t >> 6, il = t & 63;
    const int len = (ti + 1) * 64;
    const unsigned short* rowp =
        cpack + (size_t)4096 * ((size_t)ti * (ti + 1) / 2) + (size_t)il * len;
    const int nch = len >> 3;                  // 8..512 chunks of 8 elems

    for (int ch = tid; ch < nch; ch += 512) {
        union { bf16x8 v; unsigned short s[8]; } cv;
        cv.v = *(const bf16x8*)(rowp + ch * 8);
        union { int4 a[2]; int j[8]; } ji;
        ji.a[0] = *(const int4*)(idx + ch * 8);
        ji.a[1] = *(const int4*)(idx + ch * 8 + 4);
        #pragma unroll
        for (int i = 0; i < 8; ++i) {
            const int v = ji.j[i] - lo;
            if ((unsigned)v < (unsigned)VQ) {
                const float f = bf2f(cv.s[i]);
                if (f != 0.0f) atomicAdd(&hist[v], f);
            }
        }
    }
    __syncthreads();

    f32x4* orow = (f32x4*)(out + (size_t)t * VOCAB + lo);
    for (int v = tid; v < VQ / 4; v += 512)
        __builtin_nontemporal_store(hist4[v], orow + v);
}

// ---------------------------------------------------------------------------
extern "C" void kernel_launch(void* const* d_in, const int* in_sizes, int n_in,
                              void* d_out, int out_size, void* d_ws, size_t ws_size,
                              hipStream_t stream)
{
    const float* x   = (const float*)d_in[0];
    const int*   idx = (const int*)d_in[1];
    const float* Wq  = (const float*)d_in[2];
    const float* Wk  = (const float*)d_in[3];
    float* out = (float*)d_out;

    // ws: xb 8MB | WT 1MB | qk 4MB | cpack 17MB  => ~30MB
    unsigned short* xb = (unsigned short*)d_ws;
    unsigned short* WT = xb + (size_t)T * C;
    unsigned short* qk = WT + (size_t)2 * D * C;
    unsigned short* cpack = qk + (size_t)T * 2 * D;

    prep_kernel<<<dim3(2048 + 128), 256, 0, stream>>>(x, Wq, Wk, xb, WT);
    qk_mfma_kernel<<<dim3(T / 64, (2 * D) / 64), 256, 0, stream>>>(xb, WT, qk);
    qkt_mfma_kernel<<<dim3(NTILES), 256, 0, stream>>>(qk, cpack);
    row_scatter_kernel<<<dim3(T, 4), 512, 0, stream>>>(cpack, idx, out);
}